// Round 3
// baseline (423.660 us; speedup 1.0000x reference)
//
#include <hip/hip_runtime.h>
#include <hip/hip_bf16.h>

#define NN 8192
#define FF 512
#define HH 512
#define CC 64
#define K3 1536             // 3 * 512 : [hi | hi | lo] x [hi | lo | hi]
#define NS_TOTAL 557056     // 512*512 + 512*512 + 64*512
#define KSEL 278529u        // 1 + round(0.5 * (557056-1))
#define MAXNBR 96

typedef short short8 __attribute__((ext_vector_type(8)));
typedef __bf16 bf16x8 __attribute__((ext_vector_type(8)));
typedef float f32x4 __attribute__((ext_vector_type(4)));

__device__ inline unsigned short f2bf(float f) {   // RNE f32 -> bf16 bits
    unsigned u = __float_as_uint(f);
    u += 0x7fffu + ((u >> 16) & 1u);
    return (unsigned short)(u >> 16);
}
__device__ inline float bf2f(unsigned short h) {
    return __uint_as_float(((unsigned)h) << 16);
}

__device__ inline f32x4 mfma16x16x32(short8 a, short8 b, f32x4 c) {
    return __builtin_amdgcn_mfma_f32_16x16x32_bf16(
        __builtin_bit_cast(bf16x8, a), __builtin_bit_cast(bf16x8, b), c, 0, 0, 0);
}

// ---------------- threshold: exact 4x8-bit radix select over |S| bit patterns ----------------

__global__ __launch_bounds__(256) void hist8_kernel(const float* __restrict__ S0,
                                                    const float* __restrict__ S1,
                                                    const float* __restrict__ S2,
                                                    unsigned* __restrict__ hist,
                                                    const unsigned* __restrict__ sel, int pass) {
    __shared__ unsigned lh[256];
    lh[threadIdx.x] = 0;
    __syncthreads();
    unsigned prefix = 0, pmask = 0;
    int shift = 24 - 8 * pass;
    if (pass > 0) {
        prefix = sel[4];
        pmask = 0xFFFFFFFFu << (shift + 8);
    }
    int stride = gridDim.x * blockDim.x;
    for (int idx = blockIdx.x * blockDim.x + threadIdx.x; idx < NS_TOTAL; idx += stride) {
        float v = (idx < 262144) ? S0[idx] : (idx < 524288) ? S1[idx - 262144] : S2[idx - 524288];
        unsigned key = __float_as_uint(fabsf(v));
        if ((key & pmask) == prefix)
            atomicAdd(&lh[(key >> shift) & 0xffu], 1u);
    }
    __syncthreads();
    unsigned c = lh[threadIdx.x];
    if (c) atomicAdd(&hist[threadIdx.x], c);
}

__global__ void select8_kernel(const unsigned* __restrict__ hist, unsigned* __restrict__ sel,
                               int pass) {
    if (threadIdx.x != 0) return;
    unsigned k = (pass == 0) ? KSEL : sel[5];
    unsigned prefix = (pass == 0) ? 0u : sel[4];
    unsigned cum = 0; int b = 0;
    while (b < 255 && cum + hist[b] < k) { cum += hist[b]; b++; }
    int shift = 24 - 8 * pass;
    sel[4] = prefix | ((unsigned)b << shift);
    sel[5] = k - cum;
    if (pass == 3) sel[2] = prefix | (unsigned)b;
}

// ---------------- masked weights -> split-bf16 [rows][1536] = [hi | lo | hi] ----------------
// B-side layout: cols 0..511 = hi, 512..1023 = lo, 1024..1535 = hi

__global__ void mask_split_kernel(const float* __restrict__ W0, const float* __restrict__ W1,
                                  const float* __restrict__ W2, const float* __restrict__ S0,
                                  const float* __restrict__ S1, const float* __restrict__ S2,
                                  unsigned short* __restrict__ Y0, unsigned short* __restrict__ Y1,
                                  unsigned short* __restrict__ Y2, const unsigned* __restrict__ sel) {
    int idx = blockIdx.x * blockDim.x + threadIdx.x;
    if (idx >= NS_TOTAL) return;
    float thr = __uint_as_float(sel[2]);
    const float* W; const float* S; unsigned short* Y; int i;
    if (idx < 262144)      { W = W0; S = S0; Y = Y0; i = idx; }
    else if (idx < 524288) { W = W1; S = S1; Y = Y1; i = idx - 262144; }
    else                   { W = W2; S = S2; Y = Y2; i = idx - 524288; }
    float v = (fabsf(S[i]) > thr) ? W[i] : 0.f;
    unsigned short hi = f2bf(v);
    unsigned short lo = f2bf(v - bf2f(hi));
    int r = i >> 9, c = i & 511;
    size_t base = (size_t)r * K3 + c;
    Y[base] = hi;
    Y[base + 512] = lo;
    Y[base + 1024] = hi;
}

// ---------------- activation split: f32 [rows][512] -> [hi | hi | lo] ----------------
// A-side layout: cols 0..511 = hi, 512..1023 = hi, 1024..1535 = lo

__global__ void split_kernel(const float* __restrict__ X, unsigned short* __restrict__ Y) {
    int i = blockIdx.x * blockDim.x + threadIdx.x;   // one float4
    float4 v = ((const float4*)X)[i];
    int e = i * 4, r = e >> 9, c = e & 511;
    float vv[4] = {v.x, v.y, v.z, v.w};
    ushort4 hi, lo;
    unsigned short* hp = (unsigned short*)&hi;
    unsigned short* lp = (unsigned short*)&lo;
#pragma unroll
    for (int j = 0; j < 4; ++j) {
        hp[j] = f2bf(vv[j]);
        lp[j] = f2bf(vv[j] - bf2f(hp[j]));
    }
    size_t base = (size_t)r * K3 + c;
    *(ushort4*)&Y[base] = hi;
    *(ushort4*)&Y[base + 512] = hi;
    *(ushort4*)&Y[base + 1024] = lo;
}

// ---------------- adjacency: degree + neighbor extraction (one pass over 256MB) ----------------

__global__ __launch_bounds__(256) void deg_kernel(const float* __restrict__ adj,
                                                  int* __restrict__ nnz, int* __restrict__ colsI,
                                                  float* __restrict__ dis) {
    int row = blockIdx.x;
    __shared__ int cnt;
    if (threadIdx.x == 0) cnt = 0;
    __syncthreads();
    const float4* arow = (const float4*)(adj + (size_t)row * NN);
    int* cp = colsI + (size_t)row * MAXNBR;
    for (int c4 = threadIdx.x; c4 < NN / 4; c4 += 256) {
        float4 v = arow[c4];
        int base = c4 * 4;
        float vv[4] = {v.x, v.y, v.z, v.w};
#pragma unroll
        for (int kq = 0; kq < 4; ++kq) {
            int col = base + kq;
            if (vv[kq] != 0.f || col == row) {
                int s = atomicAdd(&cnt, 1);
                if (s < MAXNBR) cp[s] = col;
            }
        }
    }
    __syncthreads();
    if (threadIdx.x == 0) {
        int c = cnt;
        nnz[row] = (c < MAXNBR) ? c : MAXNBR;
        dis[row] = rsqrtf((float)c);
    }
}

// ---------------- split-bf16 MFMA GEMM: C[M,Nn] = A3[M,K3] * B3[Nn,K3]^T ----------------
// BM=128, BN=64, BK=64; 256 threads = 4 waves (2x2), wave tile 64x32 (4x2 16x16 frags)

template<int WRITE_SPLIT>
__global__ __launch_bounds__(256) void gemm_bf16s(const unsigned short* __restrict__ A,
                                                  const unsigned short* __restrict__ B,
                                                  float* __restrict__ Cf,
                                                  unsigned short* __restrict__ Cs,
                                                  int Nn) {
    constexpr int BM = 128, BN = 64, BK = 64, LDA = BK + 8;   // pad 8 elems: 2-way conflicts only
    __shared__ unsigned short As[BM * LDA];
    __shared__ unsigned short Bs[BN * LDA];
    const int tid = threadIdx.x;
    const int lane = tid & 63, wid = tid >> 6;
    const int wr = wid >> 1, wc = wid & 1;
    const int bm = blockIdx.x * BM, bn = blockIdx.y * BN;
    const int rowt = tid >> 3, colt = (tid & 7) * 8;          // staging: 8 thr/row, 16B each
    const int r16 = lane & 15, kg = lane >> 4;

    f32x4 acc[4][2] = {};
    int4 ra[4]; int4 rb[2];
#pragma unroll
    for (int i = 0; i < 4; ++i) ra[i] = *(const int4*)(A + (size_t)(bm + i * 32 + rowt) * K3 + colt);
#pragma unroll
    for (int i = 0; i < 2; ++i) rb[i] = *(const int4*)(B + (size_t)(bn + i * 32 + rowt) * K3 + colt);

    for (int k0 = 0; k0 < K3; k0 += BK) {
        __syncthreads();   // previous compute done reading LDS
#pragma unroll
        for (int i = 0; i < 4; ++i) *(int4*)&As[(i * 32 + rowt) * LDA + colt] = ra[i];
#pragma unroll
        for (int i = 0; i < 2; ++i) *(int4*)&Bs[(i * 32 + rowt) * LDA + colt] = rb[i];
        if (k0 + BK < K3) {   // prefetch next tile; latency hides under compute below
#pragma unroll
            for (int i = 0; i < 4; ++i)
                ra[i] = *(const int4*)(A + (size_t)(bm + i * 32 + rowt) * K3 + k0 + BK + colt);
#pragma unroll
            for (int i = 0; i < 2; ++i)
                rb[i] = *(const int4*)(B + (size_t)(bn + i * 32 + rowt) * K3 + k0 + BK + colt);
        }
        __syncthreads();
        const unsigned short* pA = &As[(wr * 64 + r16) * LDA + kg * 8];
        const unsigned short* pB = &Bs[(wc * 32 + r16) * LDA + kg * 8];
#pragma unroll
        for (int kk = 0; kk < 2; ++kk) {
            short8 b0 = *(const short8*)(pB + kk * 32);
            short8 b1 = *(const short8*)(pB + 16 * LDA + kk * 32);
#pragma unroll
            for (int m = 0; m < 4; ++m) {
                short8 a0 = *(const short8*)(pA + m * 16 * LDA + kk * 32);
                acc[m][0] = mfma16x16x32(a0, b0, acc[m][0]);
                acc[m][1] = mfma16x16x32(a0, b1, acc[m][1]);
            }
        }
    }
    // epilogue: C/D layout col = lane&15, row = (lane>>4)*4 + j  [m89-verified]
#pragma unroll
    for (int m = 0; m < 4; ++m) {
#pragma unroll
        for (int n = 0; n < 2; ++n) {
            int row0 = bm + wr * 64 + m * 16 + kg * 4;
            int col  = bn + wc * 32 + n * 16 + r16;
#pragma unroll
            for (int j = 0; j < 4; ++j) {
                float v = acc[m][n][j];
                if (WRITE_SPLIT) {
                    unsigned short hi = f2bf(v);
                    unsigned short lo = f2bf(v - bf2f(hi));
                    size_t base = (size_t)(row0 + j) * K3 + col;
                    Cs[base] = hi;
                    Cs[base + 512] = hi;
                    Cs[base + 1024] = lo;
                } else {
                    Cf[(size_t)(row0 + j) * Nn + col] = v;
                }
            }
        }
    }
}

// ---------------- SpMM: Hout[row,:] = dis[row] * sum_nbr dis[c] * Hin[c,:] ----------------

__global__ void spmm512(const int* __restrict__ nnz, const int* __restrict__ colsI,
                        const float* __restrict__ dis, const float* __restrict__ Hin,
                        float* __restrict__ Hout) {
    int row = blockIdx.x;
    int t = threadIdx.x;  // 128
    int cnt = nnz[row];
    const int* cp = colsI + (size_t)row * MAXNBR;
    float4 acc = make_float4(0.f, 0.f, 0.f, 0.f);
    for (int j = 0; j < cnt; ++j) {
        int c = cp[j];
        float wgt = dis[c];
        float4 v = *(const float4*)(Hin + (size_t)c * HH + t * 4);
        acc.x += wgt * v.x; acc.y += wgt * v.y; acc.z += wgt * v.z; acc.w += wgt * v.w;
    }
    float di = dis[row];
    acc.x *= di; acc.y *= di; acc.z *= di; acc.w *= di;
    *(float4*)(Hout + (size_t)row * HH + t * 4) = acc;
}

__global__ void spmm64(const int* __restrict__ nnz, const int* __restrict__ colsI,
                       const float* __restrict__ dis, const float* __restrict__ Hin,
                       float* __restrict__ Hout) {
    int row = blockIdx.x;
    int t = threadIdx.x;  // 64
    int cnt = nnz[row];
    const int* cp = colsI + (size_t)row * MAXNBR;
    float acc = 0.f;
    for (int j = 0; j < cnt; ++j) {
        int c = cp[j];
        acc += dis[c] * Hin[(size_t)c * CC + t];
    }
    Hout[(size_t)row * CC + t] = dis[row] * acc;
}

// ---------------- PairNorm ----------------

__global__ void colsum_kernel(const float* __restrict__ X, float* __restrict__ colsum) {
    int t = threadIdx.x;  // 256
    float s0 = 0.f, s1 = 0.f;
    for (int r = blockIdx.x; r < NN; r += gridDim.x) {
        const float* row = X + (size_t)r * HH;
        s0 += row[t];
        s1 += row[t + 256];
    }
    atomicAdd(&colsum[t], s0);
    atomicAdd(&colsum[t + 256], s1);
}

__global__ void sumsq_kernel(const float* __restrict__ X, const float* __restrict__ colsum,
                             float* __restrict__ stats) {
    const float4* X4 = (const float4*)X;
    const float4* M4 = (const float4*)colsum;
    const float inv = 1.0f / (float)NN;
    float local = 0.f;
    int total = NN * HH / 4;
    for (int i = blockIdx.x * blockDim.x + threadIdx.x; i < total; i += gridDim.x * blockDim.x) {
        float4 v = X4[i];
        float4 m = M4[i & 127];
        float dx = v.x - m.x * inv; local += dx * dx;
        float dy = v.y - m.y * inv; local += dy * dy;
        float dz = v.z - m.z * inv; local += dz * dz;
        float dw = v.w - m.w * inv; local += dw * dw;
    }
#pragma unroll
    for (int o = 32; o > 0; o >>= 1) local += __shfl_down(local, o);
    __shared__ float red[4];
    int wid = threadIdx.x >> 6, lane = threadIdx.x & 63;
    if (lane == 0) red[wid] = local;
    __syncthreads();
    if (threadIdx.x == 0) atomicAdd(stats, red[0] + red[1] + red[2] + red[3]);
}

// pairnorm normalize + relu, writing split-bf16 A-layout [hi | hi | lo] for the next GEMM
__global__ void pn_apply_split(const float* __restrict__ X, const float* __restrict__ colsum,
                               const float* __restrict__ stats, unsigned short* __restrict__ Y) {
    int i = blockIdx.x * blockDim.x + threadIdx.x;   // one float4; NN*HH/4 total
    const float inv = 1.0f / (float)NN;
    float s = 1.0f / sqrtf(1e-6f + stats[0] * inv);
    float4 v = ((const float4*)X)[i];
    float4 m = ((const float4*)colsum)[i & 127];
    float vv[4];
    vv[0] = fmaxf((v.x - m.x * inv) * s, 0.f);
    vv[1] = fmaxf((v.y - m.y * inv) * s, 0.f);
    vv[2] = fmaxf((v.z - m.z * inv) * s, 0.f);
    vv[3] = fmaxf((v.w - m.w * inv) * s, 0.f);
    ushort4 hi, lo;
    unsigned short* hp = (unsigned short*)&hi;
    unsigned short* lp = (unsigned short*)&lo;
#pragma unroll
    for (int j = 0; j < 4; ++j) {
        hp[j] = f2bf(vv[j]);
        lp[j] = f2bf(vv[j] - bf2f(hp[j]));
    }
    int e = i * 4, r = e >> 9, c = e & 511;
    size_t base = (size_t)r * K3 + c;
    *(ushort4*)&Y[base] = hi;
    *(ushort4*)&Y[base + 512] = hi;
    *(ushort4*)&Y[base + 1024] = lo;
}

// ---------------- launch ----------------

extern "C" void kernel_launch(void* const* d_in, const int* in_sizes, int n_in,
                              void* d_out, int out_size, void* d_ws, size_t ws_size,
                              hipStream_t stream) {
    const float* x   = (const float*)d_in[0];
    const float* adj = (const float*)d_in[1];
    const float* W0  = (const float*)d_in[2];
    const float* W1  = (const float*)d_in[3];
    const float* W2  = (const float*)d_in[4];
    const float* S0  = (const float*)d_in[5];
    const float* S1  = (const float*)d_in[6];
    const float* S2  = (const float*)d_in[7];
    float* out = (float*)d_out;

    char* w = (char*)d_ws;
    size_t off = 0;
    auto alloc = [&](size_t b) { size_t r = off; off = (off + b + 255) & ~(size_t)255; return r; };
    unsigned* hists = (unsigned*)(w + alloc(4 * 256 * 4));
    unsigned* sel   = (unsigned*)(w + alloc(256));
    float* colsum   = (float*)(w + alloc(HH * 4));
    float* stats    = (float*)(w + alloc(256));
    size_t zero_end = off;
    int* nnz   = (int*)(w + alloc(NN * 4));
    int* colsI = (int*)(w + alloc((size_t)NN * MAXNBR * 4));
    float* dis = (float*)(w + alloc(NN * 4));
    unsigned short* x3  = (unsigned short*)(w + alloc((size_t)NN * K3 * 2));
    unsigned short* W03 = (unsigned short*)(w + alloc((size_t)HH * K3 * 2));
    unsigned short* W13 = (unsigned short*)(w + alloc((size_t)HH * K3 * 2));
    unsigned short* W23 = (unsigned short*)(w + alloc((size_t)CC * K3 * 2));
    unsigned short* hA3 = (unsigned short*)(w + alloc((size_t)NN * K3 * 2));
    float* hB   = (float*)(w + alloc((size_t)NN * HH * 4));
    float* hAgg = (float*)(w + alloc((size_t)NN * HH * 4));
    unsigned short* hB3 = (unsigned short*)(w + alloc((size_t)NN * K3 * 2));
    float* h3   = (float*)(w + alloc((size_t)NN * CC * 4));
    (void)ws_size; (void)in_sizes; (void)n_in; (void)out_size;

    hipMemsetAsync(d_ws, 0, zero_end, stream);

    // threshold: exact radix select, 4 x 8-bit passes with LDS-private histograms
    for (int p = 0; p < 4; ++p) {
        hist8_kernel<<<256, 256, 0, stream>>>(S0, S1, S2, hists + p * 256, sel, p);
        select8_kernel<<<1, 64, 0, stream>>>(hists + p * 256, sel, p);
    }

    // masked weights -> split bf16 (B layout), x -> split bf16 (A layout)
    mask_split_kernel<<<NS_TOTAL / 256, 256, 0, stream>>>(W0, W1, W2, S0, S1, S2, W03, W13, W23, sel);
    split_kernel<<<NN * FF / 4 / 256, 256, 0, stream>>>(x, x3);

    // adjacency -> CSR + deg^-1/2  (single 256MB pass)
    deg_kernel<<<NN, 256, 0, stream>>>(adj, nnz, colsI, dis);

    // h0 = x @ Wm0^T (epilogue writes split A-layout) ; h1 = h0 @ Wm1^T (f32)
    gemm_bf16s<1><<<dim3(NN / 128, HH / 64), 256, 0, stream>>>(x3, W03, nullptr, hA3, HH);
    gemm_bf16s<0><<<dim3(NN / 128, HH / 64), 256, 0, stream>>>(hA3, W13, hB, nullptr, HH);

    // aggregation
    spmm512<<<NN, 128, 0, stream>>>(nnz, colsI, dis, hB, hAgg);

    // pairnorm + relu -> split bf16 A-layout
    colsum_kernel<<<256, 256, 0, stream>>>(hAgg, colsum);
    sumsq_kernel<<<1024, 256, 0, stream>>>(hAgg, colsum, stats);
    pn_apply_split<<<(NN * HH / 4) / 256, 256, 0, stream>>>(hAgg, colsum, stats, hB3);

    // h3 = hB @ Wm2^T ; out = adj_n @ h3
    gemm_bf16s<0><<<dim3(NN / 128, CC / 64), 256, 0, stream>>>(hB3, W23, h3, nullptr, CC);
    spmm64<<<NN, 64, 0, stream>>>(nnz, colsI, dis, h3, out);
}

// Round 4
// 315.046 us; speedup vs baseline: 1.3448x; 1.3448x over previous
//
#include <hip/hip_runtime.h>
#include <hip/hip_bf16.h>

#define NN 8192
#define FF 512
#define HH 512
#define CC 64
#define K3 1536             // 3 * 512 : A=[hi | hi | lo] x B=[hi | lo | hi]
#define NS_TOTAL 557056     // 512*512 + 512*512 + 64*512
#define KSEL 278529u        // 1 + round(0.5 * (557056-1))
#define MAXNBR 96

typedef short short8 __attribute__((ext_vector_type(8)));
typedef __bf16 bf16x8 __attribute__((ext_vector_type(8)));
typedef float f32x4 __attribute__((ext_vector_type(4)));

__device__ inline unsigned short f2bf(float f) {   // RNE f32 -> bf16 bits
    unsigned u = __float_as_uint(f);
    u += 0x7fffu + ((u >> 16) & 1u);
    return (unsigned short)(u >> 16);
}
__device__ inline float bf2f(unsigned short h) {
    return __uint_as_float(((unsigned)h) << 16);
}

__device__ inline f32x4 mfma16x16x32(short8 a, short8 b, f32x4 c) {
    return __builtin_amdgcn_mfma_f32_16x16x32_bf16(
        __builtin_bit_cast(bf16x8, a), __builtin_bit_cast(bf16x8, b), c, 0, 0, 0);
}

// async global->LDS, 16B per lane; LDS dest = wave-uniform base + lane*16
__device__ inline void gload_lds16(const unsigned short* g, unsigned short* l) {
    __builtin_amdgcn_global_load_lds(
        (const __attribute__((address_space(1))) void*)g,
        (__attribute__((address_space(3))) void*)l,
        16, 0, 0);
}

// ---------------- threshold: exact 4x8-bit radix select over |S| bit patterns ----------------

__global__ __launch_bounds__(256) void hist8_kernel(const float* __restrict__ S0,
                                                    const float* __restrict__ S1,
                                                    const float* __restrict__ S2,
                                                    unsigned* __restrict__ hist,
                                                    const unsigned* __restrict__ sel, int pass) {
    __shared__ unsigned lh[256];
    lh[threadIdx.x] = 0;
    __syncthreads();
    unsigned prefix = 0, pmask = 0;
    int shift = 24 - 8 * pass;
    if (pass > 0) {
        prefix = sel[4];
        pmask = 0xFFFFFFFFu << (shift + 8);
    }
    int stride = gridDim.x * blockDim.x;
    for (int idx = blockIdx.x * blockDim.x + threadIdx.x; idx < NS_TOTAL; idx += stride) {
        float v = (idx < 262144) ? S0[idx] : (idx < 524288) ? S1[idx - 262144] : S2[idx - 524288];
        unsigned key = __float_as_uint(fabsf(v));
        if ((key & pmask) == prefix)
            atomicAdd(&lh[(key >> shift) & 0xffu], 1u);
    }
    __syncthreads();
    unsigned c = lh[threadIdx.x];
    if (c) atomicAdd(&hist[threadIdx.x], c);
}

__global__ void select8_kernel(const unsigned* __restrict__ hist, unsigned* __restrict__ sel,
                               int pass) {
    if (threadIdx.x != 0) return;
    unsigned k = (pass == 0) ? KSEL : sel[5];
    unsigned prefix = (pass == 0) ? 0u : sel[4];
    unsigned cum = 0; int b = 0;
    while (b < 255 && cum + hist[b] < k) { cum += hist[b]; b++; }
    int shift = 24 - 8 * pass;
    sel[4] = prefix | ((unsigned)b << shift);
    sel[5] = k - cum;
    if (pass == 3) sel[2] = prefix | (unsigned)b;
}

// ---------------- masked weights -> split-bf16 [rows][1536] = [hi | lo | hi] ----------------

__global__ void mask_split_kernel(const float* __restrict__ W0, const float* __restrict__ W1,
                                  const float* __restrict__ W2, const float* __restrict__ S0,
                                  const float* __restrict__ S1, const float* __restrict__ S2,
                                  unsigned short* __restrict__ Y0, unsigned short* __restrict__ Y1,
                                  unsigned short* __restrict__ Y2, const unsigned* __restrict__ sel) {
    int idx = blockIdx.x * blockDim.x + threadIdx.x;
    if (idx >= NS_TOTAL) return;
    float thr = __uint_as_float(sel[2]);
    const float* W; const float* S; unsigned short* Y; int i;
    if (idx < 262144)      { W = W0; S = S0; Y = Y0; i = idx; }
    else if (idx < 524288) { W = W1; S = S1; Y = Y1; i = idx - 262144; }
    else                   { W = W2; S = S2; Y = Y2; i = idx - 524288; }
    float v = (fabsf(S[i]) > thr) ? W[i] : 0.f;
    unsigned short hi = f2bf(v);
    unsigned short lo = f2bf(v - bf2f(hi));
    int r = i >> 9, c = i & 511;
    size_t base = (size_t)r * K3 + c;
    Y[base] = hi;
    Y[base + 512] = lo;
    Y[base + 1024] = hi;
}

// ---------------- activation split: f32 [rows][512] -> [hi | hi | lo] ----------------

__global__ void split_kernel(const float* __restrict__ X, unsigned short* __restrict__ Y) {
    int i = blockIdx.x * blockDim.x + threadIdx.x;   // one float4
    float4 v = ((const float4*)X)[i];
    int e = i * 4, r = e >> 9, c = e & 511;
    float vv[4] = {v.x, v.y, v.z, v.w};
    ushort4 hi, lo;
    unsigned short* hp = (unsigned short*)&hi;
    unsigned short* lp = (unsigned short*)&lo;
#pragma unroll
    for (int j = 0; j < 4; ++j) {
        hp[j] = f2bf(vv[j]);
        lp[j] = f2bf(vv[j] - bf2f(hp[j]));
    }
    size_t base = (size_t)r * K3 + c;
    *(ushort4*)&Y[base] = hi;
    *(ushort4*)&Y[base + 512] = hi;
    *(ushort4*)&Y[base + 1024] = lo;
}

// ---------------- adjacency: degree + neighbor extraction (one pass over 256MB) ----------------

__global__ __launch_bounds__(256) void deg_kernel(const float* __restrict__ adj,
                                                  int* __restrict__ nnz, int* __restrict__ colsI,
                                                  float* __restrict__ dis) {
    int row = blockIdx.x;
    __shared__ int cnt;
    if (threadIdx.x == 0) cnt = 0;
    __syncthreads();
    const float4* arow = (const float4*)(adj + (size_t)row * NN);
    int* cp = colsI + (size_t)row * MAXNBR;
    for (int c4 = threadIdx.x; c4 < NN / 4; c4 += 256) {
        float4 v = arow[c4];
        int base = c4 * 4;
        float vv[4] = {v.x, v.y, v.z, v.w};
#pragma unroll
        for (int kq = 0; kq < 4; ++kq) {
            int col = base + kq;
            if (vv[kq] != 0.f || col == row) {
                int s = atomicAdd(&cnt, 1);
                if (s < MAXNBR) cp[s] = col;
            }
        }
    }
    __syncthreads();
    if (threadIdx.x == 0) {
        int c = cnt;
        nnz[row] = (c < MAXNBR) ? c : MAXNBR;
        dis[row] = rsqrtf((float)c);
    }
}

// ---------------- m97-structure MFMA GEMM: C[M,Nn] = A3[M,K3] * B3[Nn,K3]^T ----------------
// BM=128, BK=32, 4 waves (2x2). BN_=128: wave tile 64x64 (4x4 frags), 16 MFMA : 8 ds_read_b128
// per K-step. Staging via global_load_lds width=16 into linear LDS (no pad).

template<int BN_, int WRITE_SPLIT>
__global__ __launch_bounds__(256) void gemm97(const unsigned short* __restrict__ A,
                                              const unsigned short* __restrict__ B,
                                              float* __restrict__ Cf,
                                              unsigned short* __restrict__ Cs, int Nn) {
    constexpr int BM = 128, BK = 32;
    constexpr int NF = BN_ / 32;             // B frags per wave (4 or 2)
    __shared__ unsigned short As[BM * BK];   // linear [row][32]
    __shared__ unsigned short Bs[BN_ * BK];
    const int tid = threadIdx.x, lane = tid & 63, wid = tid >> 6;
    const int wr = wid >> 1, wc = wid & 1;
    const int bm = blockIdx.x * BM, bn = blockIdx.y * BN_;
    const int r16 = lane & 15, kg = lane >> 4;
    const int srow = lane >> 2, scol = (lane & 3) * 8;   // staging: 4 lanes/row, 16B each
    f32x4 acc[4][NF] = {};

    for (int k0 = 0; k0 < K3; k0 += BK) {
        __syncthreads();   // all waves done reading LDS from previous step
#pragma unroll
        for (int i = 0; i < 2; ++i) {        // A: 8 chunks of 1KB, 2 per wave
            int c = wid * 2 + i;
            gload_lds16(A + (size_t)(bm + c * 16 + srow) * K3 + k0 + scol, &As[c * 512]);
        }
#pragma unroll
        for (int i = 0; i < BN_ / 64; ++i) { // B: BN_/16 chunks, (BN_/64) per wave
            int c = wid * (BN_ / 64) + i;
            gload_lds16(B + (size_t)(bn + c * 16 + srow) * K3 + k0 + scol, &Bs[c * 512]);
        }
        __syncthreads();   // vmcnt(0) drain -> tiles resident
        const unsigned short* pA = &As[(wr * 64 + r16) * BK + kg * 8];
        const unsigned short* pB = &Bs[(wc * (BN_ / 2) + r16) * BK + kg * 8];
        short8 bfr[NF];
#pragma unroll
        for (int n = 0; n < NF; ++n) bfr[n] = *(const short8*)(pB + n * 16 * BK);
#pragma unroll
        for (int m = 0; m < 4; ++m) {
            short8 a = *(const short8*)(pA + m * 16 * BK);
#pragma unroll
            for (int n = 0; n < NF; ++n)
                acc[m][n] = mfma16x16x32(a, bfr[n], acc[m][n]);
        }
    }
    // epilogue: C/D layout col = lane&15, row = (lane>>4)*4 + j  [m89-verified]
#pragma unroll
    for (int m = 0; m < 4; ++m) {
#pragma unroll
        for (int n = 0; n < NF; ++n) {
            int row0 = bm + wr * 64 + m * 16 + kg * 4;
            int col  = bn + wc * (BN_ / 2) + n * 16 + r16;
#pragma unroll
            for (int j = 0; j < 4; ++j) {
                float v = acc[m][n][j];
                if (WRITE_SPLIT) {
                    unsigned short hi = f2bf(v);
                    unsigned short lo = f2bf(v - bf2f(hi));
                    size_t base = (size_t)(row0 + j) * K3 + col;
                    Cs[base] = hi;
                    Cs[base + 512] = hi;
                    Cs[base + 1024] = lo;
                } else {
                    Cf[(size_t)(row0 + j) * Nn + col] = v;
                }
            }
        }
    }
}

// ---------------- SpMM: Hout[row,:] = dis[row] * sum_nbr dis[c] * Hin[c,:] ----------------

__global__ void spmm512(const int* __restrict__ nnz, const int* __restrict__ colsI,
                        const float* __restrict__ dis, const float* __restrict__ Hin,
                        float* __restrict__ Hout) {
    int row = blockIdx.x;
    int t = threadIdx.x;  // 128
    int cnt = nnz[row];
    const int* cp = colsI + (size_t)row * MAXNBR;
    float4 acc = make_float4(0.f, 0.f, 0.f, 0.f);
    for (int j = 0; j < cnt; ++j) {
        int c = cp[j];
        float wgt = dis[c];
        float4 v = *(const float4*)(Hin + (size_t)c * HH + t * 4);
        acc.x += wgt * v.x; acc.y += wgt * v.y; acc.z += wgt * v.z; acc.w += wgt * v.w;
    }
    float di = dis[row];
    acc.x *= di; acc.y *= di; acc.z *= di; acc.w *= di;
    *(float4*)(Hout + (size_t)row * HH + t * 4) = acc;
}

__global__ void spmm64(const int* __restrict__ nnz, const int* __restrict__ colsI,
                       const float* __restrict__ dis, const float* __restrict__ Hin,
                       float* __restrict__ Hout) {
    int row = blockIdx.x;
    int t = threadIdx.x;  // 64
    int cnt = nnz[row];
    const int* cp = colsI + (size_t)row * MAXNBR;
    float acc = 0.f;
    for (int j = 0; j < cnt; ++j) {
        int c = cp[j];
        acc += dis[c] * Hin[(size_t)c * CC + t];
    }
    Hout[(size_t)row * CC + t] = dis[row] * acc;
}

// ---------------- PairNorm ----------------

__global__ void colsum_kernel(const float* __restrict__ X, float* __restrict__ colsum) {
    int t = threadIdx.x;  // 256
    float s0 = 0.f, s1 = 0.f;
    for (int r = blockIdx.x; r < NN; r += gridDim.x) {
        const float* row = X + (size_t)r * HH;
        s0 += row[t];
        s1 += row[t + 256];
    }
    atomicAdd(&colsum[t], s0);
    atomicAdd(&colsum[t + 256], s1);
}

__global__ void sumsq_kernel(const float* __restrict__ X, const float* __restrict__ colsum,
                             float* __restrict__ stats) {
    const float4* X4 = (const float4*)X;
    const float4* M4 = (const float4*)colsum;
    const float inv = 1.0f / (float)NN;
    float local = 0.f;
    int total = NN * HH / 4;
    for (int i = blockIdx.x * blockDim.x + threadIdx.x; i < total; i += gridDim.x * blockDim.x) {
        float4 v = X4[i];
        float4 m = M4[i & 127];
        float dx = v.x - m.x * inv; local += dx * dx;
        float dy = v.y - m.y * inv; local += dy * dy;
        float dz = v.z - m.z * inv; local += dz * dz;
        float dw = v.w - m.w * inv; local += dw * dw;
    }
#pragma unroll
    for (int o = 32; o > 0; o >>= 1) local += __shfl_down(local, o);
    __shared__ float red[4];
    int wid = threadIdx.x >> 6, lane = threadIdx.x & 63;
    if (lane == 0) red[wid] = local;
    __syncthreads();
    if (threadIdx.x == 0) atomicAdd(stats, red[0] + red[1] + red[2] + red[3]);
}

// pairnorm normalize + relu, writing split-bf16 A-layout [hi | hi | lo]
__global__ void pn_apply_split(const float* __restrict__ X, const float* __restrict__ colsum,
                               const float* __restrict__ stats, unsigned short* __restrict__ Y) {
    int i = blockIdx.x * blockDim.x + threadIdx.x;   // one float4; NN*HH/4 total
    const float inv = 1.0f / (float)NN;
    float s = 1.0f / sqrtf(1e-6f + stats[0] * inv);
    float4 v = ((const float4*)X)[i];
    float4 m = ((const float4*)colsum)[i & 127];
    float vv[4];
    vv[0] = fmaxf((v.x - m.x * inv) * s, 0.f);
    vv[1] = fmaxf((v.y - m.y * inv) * s, 0.f);
    vv[2] = fmaxf((v.z - m.z * inv) * s, 0.f);
    vv[3] = fmaxf((v.w - m.w * inv) * s, 0.f);
    ushort4 hi, lo;
    unsigned short* hp = (unsigned short*)&hi;
    unsigned short* lp = (unsigned short*)&lo;
#pragma unroll
    for (int j = 0; j < 4; ++j) {
        hp[j] = f2bf(vv[j]);
        lp[j] = f2bf(vv[j] - bf2f(hp[j]));
    }
    int e = i * 4, r = e >> 9, c = e & 511;
    size_t base = (size_t)r * K3 + c;
    *(ushort4*)&Y[base] = hi;
    *(ushort4*)&Y[base + 512] = hi;
    *(ushort4*)&Y[base + 1024] = lo;
}

// ---------------- launch ----------------

extern "C" void kernel_launch(void* const* d_in, const int* in_sizes, int n_in,
                              void* d_out, int out_size, void* d_ws, size_t ws_size,
                              hipStream_t stream) {
    const float* x   = (const float*)d_in[0];
    const float* adj = (const float*)d_in[1];
    const float* W0  = (const float*)d_in[2];
    const float* W1  = (const float*)d_in[3];
    const float* W2  = (const float*)d_in[4];
    const float* S0  = (const float*)d_in[5];
    const float* S1  = (const float*)d_in[6];
    const float* S2  = (const float*)d_in[7];
    float* out = (float*)d_out;

    char* w = (char*)d_ws;
    size_t off = 0;
    auto alloc = [&](size_t b) { size_t r = off; off = (off + b + 255) & ~(size_t)255; return r; };
    unsigned* hists = (unsigned*)(w + alloc(4 * 256 * 4));
    unsigned* sel   = (unsigned*)(w + alloc(256));
    float* colsum   = (float*)(w + alloc(HH * 4));
    float* stats    = (float*)(w + alloc(256));
    size_t zero_end = off;
    int* nnz   = (int*)(w + alloc(NN * 4));
    int* colsI = (int*)(w + alloc((size_t)NN * MAXNBR * 4));
    float* dis = (float*)(w + alloc(NN * 4));
    unsigned short* x3  = (unsigned short*)(w + alloc((size_t)NN * K3 * 2));
    unsigned short* W03 = (unsigned short*)(w + alloc((size_t)HH * K3 * 2));
    unsigned short* W13 = (unsigned short*)(w + alloc((size_t)HH * K3 * 2));
    unsigned short* W23 = (unsigned short*)(w + alloc((size_t)CC * K3 * 2));
    unsigned short* hA3 = (unsigned short*)(w + alloc((size_t)NN * K3 * 2));
    float* hB   = (float*)(w + alloc((size_t)NN * HH * 4));
    float* hAgg = (float*)(w + alloc((size_t)NN * HH * 4));
    unsigned short* hB3 = (unsigned short*)(w + alloc((size_t)NN * K3 * 2));
    float* h3   = (float*)(w + alloc((size_t)NN * CC * 4));
    (void)ws_size; (void)in_sizes; (void)n_in; (void)out_size;

    hipMemsetAsync(d_ws, 0, zero_end, stream);

    // threshold: exact radix select, 4 x 8-bit passes with LDS-private histograms
    for (int p = 0; p < 4; ++p) {
        hist8_kernel<<<256, 256, 0, stream>>>(S0, S1, S2, hists + p * 256, sel, p);
        select8_kernel<<<1, 64, 0, stream>>>(hists + p * 256, sel, p);
    }

    // masked weights -> split bf16 (B layout), x -> split bf16 (A layout)
    mask_split_kernel<<<NS_TOTAL / 256, 256, 0, stream>>>(W0, W1, W2, S0, S1, S2, W03, W13, W23, sel);
    split_kernel<<<NN * FF / 4 / 256, 256, 0, stream>>>(x, x3);

    // adjacency -> CSR + deg^-1/2  (single 256MB pass)
    deg_kernel<<<NN, 256, 0, stream>>>(adj, nnz, colsI, dis);

    // h0 = x @ Wm0^T (epilogue writes split A-layout) ; h1 = h0 @ Wm1^T (f32)
    gemm97<128, 1><<<dim3(NN / 128, HH / 128), 256, 0, stream>>>(x3, W03, nullptr, hA3, HH);
    gemm97<128, 0><<<dim3(NN / 128, HH / 128), 256, 0, stream>>>(hA3, W13, hB, nullptr, HH);

    // aggregation
    spmm512<<<NN, 128, 0, stream>>>(nnz, colsI, dis, hB, hAgg);

    // pairnorm + relu -> split bf16 A-layout
    colsum_kernel<<<256, 256, 0, stream>>>(hAgg, colsum);
    sumsq_kernel<<<1024, 256, 0, stream>>>(hAgg, colsum, stats);
    pn_apply_split<<<(NN * HH / 4) / 256, 256, 0, stream>>>(hAgg, colsum, stats, hB3);

    // h3 = hB @ Wm2^T ; out = adj_n @ h3
    gemm97<64, 0><<<dim3(NN / 128, CC / 64), 256, 0, stream>>>(hB3, W23, h3, nullptr, CC);
    spmm64<<<NN, 64, 0, stream>>>(nnz, colsI, dis, h3, out);
}

// Round 5
// 275.517 us; speedup vs baseline: 1.5377x; 1.1435x over previous
//
#include <hip/hip_runtime.h>
#include <hip/hip_bf16.h>

#define NN 8192
#define FF 512
#define HH 512
#define CC 64
#define K3 1536             // 3 * 512 : A=[hi | hi | lo] x B=[hi | lo | hi]
#define NS_TOTAL 557056     // 512*512 + 512*512 + 64*512
#define KSEL 278529u        // 1 + round(0.5 * (557056-1))
#define MAXNBR 96
#define MASKB 2176          // NS_TOTAL / 256

typedef short short8 __attribute__((ext_vector_type(8)));
typedef __bf16 bf16x8 __attribute__((ext_vector_type(8)));
typedef float f32x4 __attribute__((ext_vector_type(4)));

__device__ inline unsigned short f2bf(float f) {   // RNE f32 -> bf16 bits
    unsigned u = __float_as_uint(f);
    u += 0x7fffu + ((u >> 16) & 1u);
    return (unsigned short)(u >> 16);
}
__device__ inline float bf2f(unsigned short h) {
    return __uint_as_float(((unsigned)h) << 16);
}

__device__ inline f32x4 mfma16x16x32(short8 a, short8 b, f32x4 c) {
    return __builtin_amdgcn_mfma_f32_16x16x32_bf16(
        __builtin_bit_cast(bf16x8, a), __builtin_bit_cast(bf16x8, b), c, 0, 0, 0);
}

// async global->LDS, 16B per lane; LDS dest = wave-uniform base + lane*16
__device__ inline void gload_lds16(const unsigned short* g, unsigned short* l) {
    __builtin_amdgcn_global_load_lds(
        (const __attribute__((address_space(1))) void*)g,
        (__attribute__((address_space(3))) void*)l,
        16, 0, 0);
}

// in-block select: find bin b s.t. sum(hist[0..b-1]) < k <= sum(hist[0..b]).
// All 256 threads participate; result broadcast to all. (Every block computes the
// same answer -> no cross-block communication or extra launches needed.)
__device__ void isel(const unsigned* __restrict__ hist, unsigned k,
                     unsigned& bin, unsigned& krem) {
    __shared__ unsigned sh[256];
    __shared__ unsigned res[2];
    const int t = threadIdx.x;
    __syncthreads();                  // protect sh/res from previous call
    sh[t] = hist[t];
    __syncthreads();
    unsigned pre = 0;
    for (int i = 0; i < t; ++i) pre += sh[i];
    if (pre < k && k <= pre + sh[t]) { res[0] = (unsigned)t; res[1] = k - pre; }
    __syncthreads();
    bin = res[0]; krem = res[1];
}

// derive prefix (top `npass` bytes of threshold bits) + remaining rank
__device__ void isel_chain(const unsigned* __restrict__ hists, int npass,
                           unsigned& prefix, unsigned& k) {
    prefix = 0; k = KSEL;
    for (int p = 0; p < npass; ++p) {
        unsigned bin, krem;
        isel(hists + p * 256, k, bin, krem);
        prefix |= bin << (24 - 8 * p);
        k = krem;
    }
}

// ---------------- threshold: exact 4x8-bit radix select over |S| bit patterns ----------------

__global__ __launch_bounds__(256) void hist8_kernel(const float* __restrict__ S0,
                                                    const float* __restrict__ S1,
                                                    const float* __restrict__ S2,
                                                    unsigned* __restrict__ hists, int pass) {
    unsigned prefix = 0, k;
    if (pass > 0) isel_chain(hists, pass, prefix, k);
    unsigned pmask = (pass > 0) ? (0xFFFFFFFFu << (32 - 8 * pass)) : 0u;
    int shift = 24 - 8 * pass;
    __shared__ unsigned lh[256];
    lh[threadIdx.x] = 0;
    __syncthreads();
    int stride = gridDim.x * blockDim.x;
    for (int idx = blockIdx.x * blockDim.x + threadIdx.x; idx < NS_TOTAL; idx += stride) {
        float v = (idx < 262144) ? S0[idx] : (idx < 524288) ? S1[idx - 262144] : S2[idx - 524288];
        unsigned key = __float_as_uint(fabsf(v));
        if ((key & pmask) == prefix)
            atomicAdd(&lh[(key >> shift) & 0xffu], 1u);
    }
    __syncthreads();
    unsigned c = lh[threadIdx.x];
    if (c) atomicAdd(&hists[pass * 256 + threadIdx.x], c);
}

// ---------------- fused: masked weights -> split-bf16 B-layout  AND  x -> split A-layout ----
// B-side layout: cols 0..511 = hi, 512..1023 = lo, 1024..1535 = hi
// A-side layout: cols 0..511 = hi, 512..1023 = hi, 1024..1535 = lo

__global__ __launch_bounds__(256) void mask_split_fused(
        const float* __restrict__ W0, const float* __restrict__ W1,
        const float* __restrict__ W2, const float* __restrict__ S0,
        const float* __restrict__ S1, const float* __restrict__ S2,
        const unsigned* __restrict__ hists,
        unsigned short* __restrict__ Y0, unsigned short* __restrict__ Y1,
        unsigned short* __restrict__ Y2,
        const float* __restrict__ X, unsigned short* __restrict__ XS) {
    if (blockIdx.x >= MASKB) {
        // ---- x split branch (no threshold needed) ----
        int i = (blockIdx.x - MASKB) * 256 + threadIdx.x;   // one float4; 4096 blocks exactly
        float4 v = ((const float4*)X)[i];
        int e = i * 4, r = e >> 9, c = e & 511;
        float vv[4] = {v.x, v.y, v.z, v.w};
        ushort4 hi, lo;
        unsigned short* hp = (unsigned short*)&hi;
        unsigned short* lp = (unsigned short*)&lo;
#pragma unroll
        for (int j = 0; j < 4; ++j) {
            hp[j] = f2bf(vv[j]);
            lp[j] = f2bf(vv[j] - bf2f(hp[j]));
        }
        size_t base = (size_t)r * K3 + c;
        *(ushort4*)&XS[base] = hi;
        *(ushort4*)&XS[base + 512] = hi;
        *(ushort4*)&XS[base + 1024] = lo;
        return;
    }
    // ---- mask branch: derive threshold from the 4 histograms, then mask+split ----
    unsigned prefix, k;
    isel_chain(hists, 4, prefix, k);
    float thr = __uint_as_float(prefix);
    int idx = blockIdx.x * 256 + threadIdx.x;           // < NS_TOTAL exactly
    const float* W; const float* S; unsigned short* Y; int i;
    if (idx < 262144)      { W = W0; S = S0; Y = Y0; i = idx; }
    else if (idx < 524288) { W = W1; S = S1; Y = Y1; i = idx - 262144; }
    else                   { W = W2; S = S2; Y = Y2; i = idx - 524288; }
    float v = (fabsf(S[i]) > thr) ? W[i] : 0.f;
    unsigned short hi = f2bf(v);
    unsigned short lo = f2bf(v - bf2f(hi));
    int r = i >> 9, c = i & 511;
    size_t base = (size_t)r * K3 + c;
    Y[base] = hi;
    Y[base + 512] = lo;
    Y[base + 1024] = hi;
}

// ---------------- adjacency: degree + neighbor extraction (one pass over 256MB) ----------------

__global__ __launch_bounds__(256) void deg_kernel(const float* __restrict__ adj,
                                                  int* __restrict__ nnz, int* __restrict__ colsI,
                                                  float* __restrict__ dis) {
    int row = blockIdx.x;
    __shared__ int cnt;
    if (threadIdx.x == 0) cnt = 0;
    __syncthreads();
    const float4* arow = (const float4*)(adj + (size_t)row * NN);
    int* cp = colsI + (size_t)row * MAXNBR;
    for (int c4 = threadIdx.x; c4 < NN / 4; c4 += 256) {
        float4 v = arow[c4];
        int base = c4 * 4;
        float vv[4] = {v.x, v.y, v.z, v.w};
#pragma unroll
        for (int kq = 0; kq < 4; ++kq) {
            int col = base + kq;
            if (vv[kq] != 0.f || col == row) {
                int s = atomicAdd(&cnt, 1);
                if (s < MAXNBR) cp[s] = col;
            }
        }
    }
    __syncthreads();
    if (threadIdx.x == 0) {
        int c = cnt;
        nnz[row] = (c < MAXNBR) ? c : MAXNBR;
        dis[row] = rsqrtf((float)c);
    }
}

// ---------------- m97-structure MFMA GEMM: C[M,Nn] = A3[M,K3] * B3[Nn,K3]^T ----------------
// BK=32, 4 waves (2x2). BM=64/BN=128 -> grid 512 = 2 blocks/CU (hide barrier drains).
// Staging via global_load_lds width=16 into linear LDS.

template<int BMt, int BNt, int WRITE_SPLIT>
__global__ __launch_bounds__(256) void gemm97(const unsigned short* __restrict__ A,
                                              const unsigned short* __restrict__ B,
                                              float* __restrict__ Cf,
                                              unsigned short* __restrict__ Cs, int Nn) {
    constexpr int BK = 32;
    constexpr int MF = BMt / 32;             // m frags per wave
    constexpr int NF = BNt / 32;             // n frags per wave
    __shared__ __align__(16) unsigned short As[BMt * BK];
    __shared__ __align__(16) unsigned short Bs[BNt * BK];
    const int tid = threadIdx.x, lane = tid & 63, wid = tid >> 6;
    const int wr = wid >> 1, wc = wid & 1;
    const int bm = blockIdx.x * BMt, bn = blockIdx.y * BNt;
    const int r16 = lane & 15, kg = lane >> 4;
    const int srow = lane >> 2, scol = (lane & 3) * 8;   // staging: 4 lanes/row, 16B each
    f32x4 acc[MF][NF] = {};

    for (int k0 = 0; k0 < K3; k0 += BK) {
        __syncthreads();   // all waves done reading LDS from previous step
#pragma unroll
        for (int i = 0; i < BMt / 64; ++i) {
            int c = wid * (BMt / 64) + i;
            gload_lds16(A + (size_t)(bm + c * 16 + srow) * K3 + k0 + scol, &As[c * 512]);
        }
#pragma unroll
        for (int i = 0; i < BNt / 64; ++i) {
            int c = wid * (BNt / 64) + i;
            gload_lds16(B + (size_t)(bn + c * 16 + srow) * K3 + k0 + scol, &Bs[c * 512]);
        }
        __syncthreads();   // vmcnt(0) drain -> tiles resident
        const unsigned short* pA = &As[(wr * (BMt / 2) + r16) * BK + kg * 8];
        const unsigned short* pB = &Bs[(wc * (BNt / 2) + r16) * BK + kg * 8];
        short8 bfr[NF];
#pragma unroll
        for (int n = 0; n < NF; ++n) bfr[n] = *(const short8*)(pB + n * 16 * BK);
#pragma unroll
        for (int m = 0; m < MF; ++m) {
            short8 a = *(const short8*)(pA + m * 16 * BK);
#pragma unroll
            for (int n = 0; n < NF; ++n)
                acc[m][n] = mfma16x16x32(a, bfr[n], acc[m][n]);
        }
    }
    // epilogue: C/D layout col = lane&15, row = (lane>>4)*4 + j  [m89-verified]
#pragma unroll
    for (int m = 0; m < MF; ++m) {
#pragma unroll
        for (int n = 0; n < NF; ++n) {
            int row0 = bm + wr * (BMt / 2) + m * 16 + kg * 4;
            int col  = bn + wc * (BNt / 2) + n * 16 + r16;
#pragma unroll
            for (int j = 0; j < 4; ++j) {
                float v = acc[m][n][j];
                if (WRITE_SPLIT) {
                    unsigned short hi = f2bf(v);
                    unsigned short lo = f2bf(v - bf2f(hi));
                    size_t base = (size_t)(row0 + j) * K3 + col;
                    Cs[base] = hi;
                    Cs[base + 512] = hi;
                    Cs[base + 1024] = lo;
                } else {
                    Cf[(size_t)(row0 + j) * Nn + col] = v;
                }
            }
        }
    }
}

// ---------------- SpMM: Hout[row,:] = dis[row] * sum_nbr dis[c] * Hin[c,:] ----------------

__global__ void spmm512(const int* __restrict__ nnz, const int* __restrict__ colsI,
                        const float* __restrict__ dis, const float* __restrict__ Hin,
                        float* __restrict__ Hout) {
    int row = blockIdx.x;
    int t = threadIdx.x;  // 128
    int cnt = nnz[row];
    const int* cp = colsI + (size_t)row * MAXNBR;
    float4 acc = make_float4(0.f, 0.f, 0.f, 0.f);
    for (int j = 0; j < cnt; ++j) {
        int c = cp[j];
        float wgt = dis[c];
        float4 v = *(const float4*)(Hin + (size_t)c * HH + t * 4);
        acc.x += wgt * v.x; acc.y += wgt * v.y; acc.z += wgt * v.z; acc.w += wgt * v.w;
    }
    float di = dis[row];
    acc.x *= di; acc.y *= di; acc.z *= di; acc.w *= di;
    *(float4*)(Hout + (size_t)row * HH + t * 4) = acc;
}

__global__ void spmm64(const int* __restrict__ nnz, const int* __restrict__ colsI,
                       const float* __restrict__ dis, const float* __restrict__ Hin,
                       float* __restrict__ Hout) {
    int row = blockIdx.x;
    int t = threadIdx.x;  // 64
    int cnt = nnz[row];
    const int* cp = colsI + (size_t)row * MAXNBR;
    float acc = 0.f;
    for (int j = 0; j < cnt; ++j) {
        int c = cp[j];
        acc += dis[c] * Hin[(size_t)c * CC + t];
    }
    Hout[(size_t)row * CC + t] = dis[row] * acc;
}

// ---------------- PairNorm (fused stats): colsum + total sum-of-squares in one pass ------------
// sum |x - m|^2 = sum x^2 - (sum_c colsum_c^2)/N  -> no second data pass needed.

__global__ void colstats_kernel(const float* __restrict__ X, float* __restrict__ colsum,
                                float* __restrict__ stats) {
    int t = threadIdx.x;  // 256 threads, 256 blocks
    float s0 = 0.f, s1 = 0.f, sq = 0.f;
    for (int r = blockIdx.x; r < NN; r += 256) {
        const float* row = X + (size_t)r * HH;
        float a = row[t], b = row[t + 256];
        s0 += a; s1 += b;
        sq += a * a + b * b;
    }
    atomicAdd(&colsum[t], s0);
    atomicAdd(&colsum[t + 256], s1);
#pragma unroll
    for (int o = 32; o > 0; o >>= 1) sq += __shfl_down(sq, o);
    __shared__ float red[4];
    int wv = t >> 6, lane = t & 63;
    if (lane == 0) red[wv] = sq;
    __syncthreads();
    if (t == 0) atomicAdd(stats, red[0] + red[1] + red[2] + red[3]);
}

// pairnorm normalize + relu, writing split-bf16 A-layout [hi | hi | lo].
// Each block derives s from stats (sum x^2) and colsum (via sum colsum^2) locally.
__global__ __launch_bounds__(256) void pn_apply_split(const float* __restrict__ X,
                                                      const float* __restrict__ colsum,
                                                      const float* __restrict__ stats,
                                                      unsigned short* __restrict__ Y) {
    const float inv = 1.0f / (float)NN;
    int t = threadIdx.x;
    // block-local: msum = sum_c colsum[c]^2
    float c0 = colsum[t], c1 = colsum[t + 256];
    float sq = c0 * c0 + c1 * c1;
#pragma unroll
    for (int o = 32; o > 0; o >>= 1) sq += __shfl_down(sq, o);
    __shared__ float red[4];
    __shared__ float sbc;
    int wv = t >> 6, lane = t & 63;
    if (lane == 0) red[wv] = sq;
    __syncthreads();
    if (t == 0) {
        float msum = red[0] + red[1] + red[2] + red[3];
        sbc = 1.0f / sqrtf(1e-6f + (stats[0] - msum * inv) * inv);
    }
    __syncthreads();
    float s = sbc;

    int i = blockIdx.x * 256 + t;   // one float4; NN*HH/4 total
    float4 v = ((const float4*)X)[i];
    float4 m = ((const float4*)colsum)[i & 127];
    float vv[4];
    vv[0] = fmaxf((v.x - m.x * inv) * s, 0.f);
    vv[1] = fmaxf((v.y - m.y * inv) * s, 0.f);
    vv[2] = fmaxf((v.z - m.z * inv) * s, 0.f);
    vv[3] = fmaxf((v.w - m.w * inv) * s, 0.f);
    ushort4 hi, lo;
    unsigned short* hp = (unsigned short*)&hi;
    unsigned short* lp = (unsigned short*)&lo;
#pragma unroll
    for (int j = 0; j < 4; ++j) {
        hp[j] = f2bf(vv[j]);
        lp[j] = f2bf(vv[j] - bf2f(hp[j]));
    }
    int e = i * 4, r = e >> 9, c = e & 511;
    size_t base = (size_t)r * K3 + c;
    *(ushort4*)&Y[base] = hi;
    *(ushort4*)&Y[base + 512] = hi;
    *(ushort4*)&Y[base + 1024] = lo;
}

// ---------------- launch ----------------

extern "C" void kernel_launch(void* const* d_in, const int* in_sizes, int n_in,
                              void* d_out, int out_size, void* d_ws, size_t ws_size,
                              hipStream_t stream) {
    const float* x   = (const float*)d_in[0];
    const float* adj = (const float*)d_in[1];
    const float* W0  = (const float*)d_in[2];
    const float* W1  = (const float*)d_in[3];
    const float* W2  = (const float*)d_in[4];
    const float* S0  = (const float*)d_in[5];
    const float* S1  = (const float*)d_in[6];
    const float* S2  = (const float*)d_in[7];
    float* out = (float*)d_out;

    char* w = (char*)d_ws;
    size_t off = 0;
    auto alloc = [&](size_t b) { size_t r = off; off = (off + b + 255) & ~(size_t)255; return r; };
    unsigned* hists = (unsigned*)(w + alloc(4 * 256 * 4));   // hists[pass][256]
    float* colsum   = (float*)(w + alloc(HH * 4));
    float* stats    = (float*)(w + alloc(256));
    size_t zero_end = off;
    int* nnz   = (int*)(w + alloc(NN * 4));
    int* colsI = (int*)(w + alloc((size_t)NN * MAXNBR * 4));
    float* dis = (float*)(w + alloc(NN * 4));
    unsigned short* x3  = (unsigned short*)(w + alloc((size_t)NN * K3 * 2));
    unsigned short* W03 = (unsigned short*)(w + alloc((size_t)HH * K3 * 2));
    unsigned short* W13 = (unsigned short*)(w + alloc((size_t)HH * K3 * 2));
    unsigned short* W23 = (unsigned short*)(w + alloc((size_t)CC * K3 * 2));
    unsigned short* hA3 = (unsigned short*)(w + alloc((size_t)NN * K3 * 2));
    float* hB   = (float*)(w + alloc((size_t)NN * HH * 4));
    float* hAgg = (float*)(w + alloc((size_t)NN * HH * 4));
    unsigned short* hB3 = (unsigned short*)(w + alloc((size_t)NN * K3 * 2));
    float* h3   = (float*)(w + alloc((size_t)NN * CC * 4));
    (void)ws_size; (void)in_sizes; (void)n_in; (void)out_size;

    hipMemsetAsync(d_ws, 0, zero_end, stream);

    // threshold: exact radix select, 4 x 8-bit histogram passes.
    // select of pass p-1 is re-derived in-block by pass p (isel_chain) -> no select launches.
    for (int p = 0; p < 4; ++p)
        hist8_kernel<<<256, 256, 0, stream>>>(S0, S1, S2, hists, p);

    // fused: masked weights -> split bf16 (B layout)  AND  x -> split bf16 (A layout)
    mask_split_fused<<<MASKB + NN * FF / 4 / 256, 256, 0, stream>>>(
        W0, W1, W2, S0, S1, S2, hists, W03, W13, W23, x, x3);

    // adjacency -> CSR + deg^-1/2  (single 256MB pass)
    deg_kernel<<<NN, 256, 0, stream>>>(adj, nnz, colsI, dis);

    // h0 = x @ Wm0^T (epilogue writes split A-layout) ; h1 = h0 @ Wm1^T (f32)
    gemm97<64, 128, 1><<<dim3(NN / 64, HH / 128), 256, 0, stream>>>(x3, W03, nullptr, hA3, HH);
    gemm97<64, 128, 0><<<dim3(NN / 64, HH / 128), 256, 0, stream>>>(hA3, W13, hB, nullptr, HH);

    // aggregation
    spmm512<<<NN, 128, 0, stream>>>(nnz, colsI, dis, hB, hAgg);

    // pairnorm stats (single fused pass) + apply+relu -> split bf16 A-layout
    colstats_kernel<<<256, 256, 0, stream>>>(hAgg, colsum, stats);
    pn_apply_split<<<(NN * HH / 4) / 256, 256, 0, stream>>>(hAgg, colsum, stats, hB3);

    // h3 = hB @ Wm2^T ; out = adj_n @ h3
    gemm97<64, 64, 0><<<dim3(NN / 64, CC / 64), 256, 0, stream>>>(hB3, W23, h3, nullptr, CC);
    spmm64<<<NN, 64, 0, stream>>>(nnz, colsI, dis, h3, out);
}

// Round 6
// 245.998 us; speedup vs baseline: 1.7222x; 1.1200x over previous
//
#include <hip/hip_runtime.h>
#include <hip/hip_bf16.h>

#define NN 8192
#define FF 512
#define HH 512
#define CC 64
#define NS_TOTAL 557056     // 512*512 + 512*512 + 64*512
#define KSEL 278529u        // 1 + round(0.5 * (557056-1))
#define MAXNBR 96
#define MASKB 2176          // NS_TOTAL / 256

typedef short short8 __attribute__((ext_vector_type(8)));
typedef __bf16 bf16x8 __attribute__((ext_vector_type(8)));
typedef float f32x4 __attribute__((ext_vector_type(4)));

__device__ inline unsigned short f2bf(float f) {   // RNE f32 -> bf16 bits
    unsigned u = __float_as_uint(f);
    u += 0x7fffu + ((u >> 16) & 1u);
    return (unsigned short)(u >> 16);
}
__device__ inline float bf2f(unsigned short h) {
    return __uint_as_float(((unsigned)h) << 16);
}

__device__ inline f32x4 mfma16x16x32(short8 a, short8 b, f32x4 c) {
    return __builtin_amdgcn_mfma_f32_16x16x32_bf16(
        __builtin_bit_cast(bf16x8, a), __builtin_bit_cast(bf16x8, b), c, 0, 0, 0);
}

// async global->LDS, 16B per lane; LDS dest = wave-uniform base + lane*16
__device__ inline void gload_lds16(const unsigned short* g, unsigned short* l) {
    __builtin_amdgcn_global_load_lds(
        (const __attribute__((address_space(1))) void*)g,
        (__attribute__((address_space(3))) void*)l,
        16, 0, 0);
}

// in-block select: find bin b s.t. sum(hist[0..b-1]) < k <= sum(hist[0..b]).
__device__ void isel(const unsigned* __restrict__ hist, unsigned k,
                     unsigned& bin, unsigned& krem) {
    __shared__ unsigned sh[256];
    __shared__ unsigned res[2];
    const int t = threadIdx.x;
    __syncthreads();                  // protect sh/res from previous call
    sh[t] = hist[t];
    __syncthreads();
    unsigned pre = 0;
    for (int i = 0; i < t; ++i) pre += sh[i];
    if (pre < k && k <= pre + sh[t]) { res[0] = (unsigned)t; res[1] = k - pre; }
    __syncthreads();
    bin = res[0]; krem = res[1];
}

__device__ void isel_chain(const unsigned* __restrict__ hists, int npass,
                           unsigned& prefix, unsigned& k) {
    prefix = 0; k = KSEL;
    for (int p = 0; p < npass; ++p) {
        unsigned bin, krem;
        isel(hists + p * 256, k, bin, krem);
        prefix |= bin << (24 - 8 * p);
        k = krem;
    }
}

// ---------------- threshold: exact 4x8-bit radix select over |S| bit patterns ----------------

__global__ __launch_bounds__(256) void hist8_kernel(const float* __restrict__ S0,
                                                    const float* __restrict__ S1,
                                                    const float* __restrict__ S2,
                                                    unsigned* __restrict__ hists, int pass) {
    unsigned prefix = 0, k;
    if (pass > 0) isel_chain(hists, pass, prefix, k);
    unsigned pmask = (pass > 0) ? (0xFFFFFFFFu << (32 - 8 * pass)) : 0u;
    int shift = 24 - 8 * pass;
    __shared__ unsigned lh[256];
    lh[threadIdx.x] = 0;
    __syncthreads();
    int stride = gridDim.x * blockDim.x;
    for (int idx = blockIdx.x * blockDim.x + threadIdx.x; idx < NS_TOTAL; idx += stride) {
        float v = (idx < 262144) ? S0[idx] : (idx < 524288) ? S1[idx - 262144] : S2[idx - 524288];
        unsigned key = __float_as_uint(fabsf(v));
        if ((key & pmask) == prefix)
            atomicAdd(&lh[(key >> shift) & 0xffu], 1u);
    }
    __syncthreads();
    unsigned c = lh[threadIdx.x];
    if (c) atomicAdd(&hists[pass * 256 + threadIdx.x], c);
}

// ---------------- fused: masked weights -> hi/lo bf16  AND  x -> hi/lo bf16 ----------------

__global__ __launch_bounds__(256) void mask_split_fused(
        const float* __restrict__ W0, const float* __restrict__ W1,
        const float* __restrict__ W2, const float* __restrict__ S0,
        const float* __restrict__ S1, const float* __restrict__ S2,
        const unsigned* __restrict__ hists,
        unsigned short* __restrict__ W0h, unsigned short* __restrict__ W0l,
        unsigned short* __restrict__ W1h, unsigned short* __restrict__ W1l,
        unsigned short* __restrict__ W2h, unsigned short* __restrict__ W2l,
        const float* __restrict__ X,
        unsigned short* __restrict__ Xh, unsigned short* __restrict__ Xl) {
    if (blockIdx.x >= MASKB) {
        // ---- x split branch ----
        int i = (blockIdx.x - MASKB) * 256 + threadIdx.x;   // one float4; 4096 blocks
        float4 v = ((const float4*)X)[i];
        float vv[4] = {v.x, v.y, v.z, v.w};
        ushort4 hi, lo;
        unsigned short* hp = (unsigned short*)&hi;
        unsigned short* lp = (unsigned short*)&lo;
#pragma unroll
        for (int j = 0; j < 4; ++j) {
            hp[j] = f2bf(vv[j]);
            lp[j] = f2bf(vv[j] - bf2f(hp[j]));
        }
        *(ushort4*)&Xh[(size_t)i * 4] = hi;
        *(ushort4*)&Xl[(size_t)i * 4] = lo;
        return;
    }
    // ---- mask branch ----
    unsigned prefix, k;
    isel_chain(hists, 4, prefix, k);
    float thr = __uint_as_float(prefix);
    int idx = blockIdx.x * 256 + threadIdx.x;           // < NS_TOTAL exactly
    const float* W; const float* S; unsigned short* Yh; unsigned short* Yl; int i;
    if (idx < 262144)      { W = W0; S = S0; Yh = W0h; Yl = W0l; i = idx; }
    else if (idx < 524288) { W = W1; S = S1; Yh = W1h; Yl = W1l; i = idx - 262144; }
    else                   { W = W2; S = S2; Yh = W2h; Yl = W2l; i = idx - 524288; }
    float v = (fabsf(S[i]) > thr) ? W[i] : 0.f;
    unsigned short hi = f2bf(v);
    Yh[i] = hi;
    Yl[i] = f2bf(v - bf2f(hi));
}

// ---------------- hi/lo 3-term MFMA GEMM (+ optional trailing deg blocks) ----------------
// C = Ah*Bh^T + Ah*Bl^T + Al*Bh^T over K=512. BK=32, 4 waves (2x2).
// Per K-step per wave: 12 ds_read_b128 : 24 MFMA (BM64/BN128); 16 K-steps total.
// Trailing blocks (>= gemmBlocks) run deg rows: one pass over adj, overlapped with GEMM.

template<int BMt, int BNt, int WRITE_SPLIT>
__global__ __launch_bounds__(256) void gemm_hl(
        const unsigned short* __restrict__ Ah, const unsigned short* __restrict__ Al,
        const unsigned short* __restrict__ Bh, const unsigned short* __restrict__ Bl,
        float* __restrict__ Cf, unsigned short* __restrict__ Ch,
        unsigned short* __restrict__ Cl, int Nn, int gridN, int gemmBlocks,
        const float* __restrict__ adj, int* __restrict__ nnz, int* __restrict__ colsI,
        float* __restrict__ dis, int degRow0) {
    constexpr int BK = 32;
    constexpr int MF = BMt / 32, NF = BNt / 32;
    __shared__ __align__(16) unsigned short AhS[BMt * BK], AlS[BMt * BK];
    __shared__ __align__(16) unsigned short BhS[BNt * BK], BlS[BNt * BK];
    __shared__ int dcnt;

    if ((int)blockIdx.x >= gemmBlocks) {
        // ---- deg branch: one adjacency row per block ----
        int row = degRow0 + (int)blockIdx.x - gemmBlocks;
        if (threadIdx.x == 0) dcnt = 0;
        __syncthreads();
        const float4* arow = (const float4*)(adj + (size_t)row * NN);
        int* cp = colsI + (size_t)row * MAXNBR;
        for (int c4 = threadIdx.x; c4 < NN / 4; c4 += 256) {
            float4 v = arow[c4];
            int base = c4 * 4;
            float vv[4] = {v.x, v.y, v.z, v.w};
#pragma unroll
            for (int kq = 0; kq < 4; ++kq) {
                int col = base + kq;
                if (vv[kq] != 0.f || col == row) {
                    int s = atomicAdd(&dcnt, 1);
                    if (s < MAXNBR) cp[s] = col;
                }
            }
        }
        __syncthreads();
        if (threadIdx.x == 0) {
            int c = dcnt;
            nnz[row] = (c < MAXNBR) ? c : MAXNBR;
            dis[row] = rsqrtf((float)c);
        }
        return;
    }
    // ---- gemm branch ----
    const int tid = threadIdx.x, lane = tid & 63, wid = tid >> 6;
    const int wr = wid >> 1, wc = wid & 1;
    const int bm = ((int)blockIdx.x / gridN) * BMt;
    const int bn = ((int)blockIdx.x % gridN) * BNt;
    const int r16 = lane & 15, kg = lane >> 4;
    const int srow = lane >> 2, scol = (lane & 3) * 8;   // 4 lanes/row, 16B each
    constexpr int cA = BMt / 16, cB = BNt / 16, CPW = (2 * cA + 2 * cB) / 4;
    f32x4 acc[MF][NF] = {};

    for (int k0 = 0; k0 < 512; k0 += BK) {
        __syncthreads();   // previous compute done reading LDS
#pragma unroll
        for (int i = 0; i < CPW; ++i) {
            int c = wid * CPW + i;
            const unsigned short* src; unsigned short* dst; int cc, r0;
            if (c < cA)               { src = Ah; dst = AhS; cc = c;              r0 = bm + cc * 16; }
            else if (c < 2 * cA)      { src = Al; dst = AlS; cc = c - cA;         r0 = bm + cc * 16; }
            else if (c < 2 * cA + cB) { src = Bh; dst = BhS; cc = c - 2 * cA;     r0 = bn + cc * 16; }
            else                      { src = Bl; dst = BlS; cc = c - 2 * cA - cB; r0 = bn + cc * 16; }
            gload_lds16(src + (size_t)(r0 + srow) * 512 + k0 + scol, dst + cc * 512);
        }
        __syncthreads();   // tiles resident
        const unsigned short* pAh = &AhS[(wr * (BMt / 2) + r16) * BK + kg * 8];
        const unsigned short* pAl = &AlS[(wr * (BMt / 2) + r16) * BK + kg * 8];
        const unsigned short* pBh = &BhS[(wc * (BNt / 2) + r16) * BK + kg * 8];
        const unsigned short* pBl = &BlS[(wc * (BNt / 2) + r16) * BK + kg * 8];
        short8 bh[NF], bl[NF];
#pragma unroll
        for (int n = 0; n < NF; ++n) {
            bh[n] = *(const short8*)(pBh + n * 16 * BK);
            bl[n] = *(const short8*)(pBl + n * 16 * BK);
        }
#pragma unroll
        for (int m = 0; m < MF; ++m) {
            short8 ah = *(const short8*)(pAh + m * 16 * BK);
            short8 al = *(const short8*)(pAl + m * 16 * BK);
#pragma unroll
            for (int n = 0; n < NF; ++n) {
                acc[m][n] = mfma16x16x32(ah, bh[n], acc[m][n]);
                acc[m][n] = mfma16x16x32(ah, bl[n], acc[m][n]);
                acc[m][n] = mfma16x16x32(al, bh[n], acc[m][n]);
            }
        }
    }
    // epilogue: C/D layout col = lane&15, row = (lane>>4)*4 + j  [m89-verified]
#pragma unroll
    for (int m = 0; m < MF; ++m) {
#pragma unroll
        for (int n = 0; n < NF; ++n) {
            int row0 = bm + wr * (BMt / 2) + m * 16 + kg * 4;
            int col  = bn + wc * (BNt / 2) + n * 16 + r16;
#pragma unroll
            for (int j = 0; j < 4; ++j) {
                float v = acc[m][n][j];
                if (WRITE_SPLIT) {
                    unsigned short hi = f2bf(v);
                    size_t base = (size_t)(row0 + j) * Nn + col;
                    Ch[base] = hi;
                    Cl[base] = f2bf(v - bf2f(hi));
                } else {
                    Cf[(size_t)(row0 + j) * Nn + col] = v;
                }
            }
        }
    }
}

// ---------------- SpMM: Hout[row,:] = dis[row] * sum_nbr dis[c] * Hin[c,:] ----------------

__global__ void spmm512(const int* __restrict__ nnz, const int* __restrict__ colsI,
                        const float* __restrict__ dis, const float* __restrict__ Hin,
                        float* __restrict__ Hout) {
    int row = blockIdx.x;
    int t = threadIdx.x;  // 128
    int cnt = nnz[row];
    const int* cp = colsI + (size_t)row * MAXNBR;
    float4 acc = make_float4(0.f, 0.f, 0.f, 0.f);
    for (int j = 0; j < cnt; ++j) {
        int c = cp[j];
        float wgt = dis[c];
        float4 v = *(const float4*)(Hin + (size_t)c * HH + t * 4);
        acc.x += wgt * v.x; acc.y += wgt * v.y; acc.z += wgt * v.z; acc.w += wgt * v.w;
    }
    float di = dis[row];
    acc.x *= di; acc.y *= di; acc.z *= di; acc.w *= di;
    *(float4*)(Hout + (size_t)row * HH + t * 4) = acc;
}

__global__ void spmm64(const int* __restrict__ nnz, const int* __restrict__ colsI,
                       const float* __restrict__ dis, const float* __restrict__ Hin,
                       float* __restrict__ Hout) {
    int row = blockIdx.x;
    int t = threadIdx.x;  // 64
    int cnt = nnz[row];
    const int* cp = colsI + (size_t)row * MAXNBR;
    float acc = 0.f;
    for (int j = 0; j < cnt; ++j) {
        int c = cp[j];
        acc += dis[c] * Hin[(size_t)c * CC + t];
    }
    Hout[(size_t)row * CC + t] = dis[row] * acc;
}

// ---------------- PairNorm (fused stats): colsum + total sum-of-squares in one pass ----------

__global__ void colstats_kernel(const float* __restrict__ X, float* __restrict__ colsum,
                                float* __restrict__ stats) {
    int t = threadIdx.x;  // 256 threads, 256 blocks
    float s0 = 0.f, s1 = 0.f, sq = 0.f;
    for (int r = blockIdx.x; r < NN; r += 256) {
        const float* row = X + (size_t)r * HH;
        float a = row[t], b = row[t + 256];
        s0 += a; s1 += b;
        sq += a * a + b * b;
    }
    atomicAdd(&colsum[t], s0);
    atomicAdd(&colsum[t + 256], s1);
#pragma unroll
    for (int o = 32; o > 0; o >>= 1) sq += __shfl_down(sq, o);
    __shared__ float red[4];
    int wv = t >> 6, lane = t & 63;
    if (lane == 0) red[wv] = sq;
    __syncthreads();
    if (t == 0) atomicAdd(stats, red[0] + red[1] + red[2] + red[3]);
}

// pairnorm normalize + relu -> hi/lo bf16 arrays
__global__ __launch_bounds__(256) void pn_apply_split(const float* __restrict__ X,
                                                      const float* __restrict__ colsum,
                                                      const float* __restrict__ stats,
                                                      unsigned short* __restrict__ Yh,
                                                      unsigned short* __restrict__ Yl) {
    const float inv = 1.0f / (float)NN;
    int t = threadIdx.x;
    // block-local: msum = sum_c colsum[c]^2 ;  sum|x-m|^2 = stats - msum/N
    float c0 = colsum[t], c1 = colsum[t + 256];
    float sq = c0 * c0 + c1 * c1;
#pragma unroll
    for (int o = 32; o > 0; o >>= 1) sq += __shfl_down(sq, o);
    __shared__ float red[4];
    __shared__ float sbc;
    int wv = t >> 6, lane = t & 63;
    if (lane == 0) red[wv] = sq;
    __syncthreads();
    if (t == 0) {
        float msum = red[0] + red[1] + red[2] + red[3];
        sbc = 1.0f / sqrtf(1e-6f + (stats[0] - msum * inv) * inv);
    }
    __syncthreads();
    float s = sbc;

    int i = blockIdx.x * 256 + t;   // one float4; NN*HH/4 total
    float4 v = ((const float4*)X)[i];
    float4 m = ((const float4*)colsum)[i & 127];
    float vv[4];
    vv[0] = fmaxf((v.x - m.x * inv) * s, 0.f);
    vv[1] = fmaxf((v.y - m.y * inv) * s, 0.f);
    vv[2] = fmaxf((v.z - m.z * inv) * s, 0.f);
    vv[3] = fmaxf((v.w - m.w * inv) * s, 0.f);
    ushort4 hi, lo;
    unsigned short* hp = (unsigned short*)&hi;
    unsigned short* lp = (unsigned short*)&lo;
#pragma unroll
    for (int j = 0; j < 4; ++j) {
        hp[j] = f2bf(vv[j]);
        lp[j] = f2bf(vv[j] - bf2f(hp[j]));
    }
    *(ushort4*)&Yh[(size_t)i * 4] = hi;
    *(ushort4*)&Yl[(size_t)i * 4] = lo;
}

// ---------------- launch ----------------

extern "C" void kernel_launch(void* const* d_in, const int* in_sizes, int n_in,
                              void* d_out, int out_size, void* d_ws, size_t ws_size,
                              hipStream_t stream) {
    const float* x   = (const float*)d_in[0];
    const float* adj = (const float*)d_in[1];
    const float* W0  = (const float*)d_in[2];
    const float* W1  = (const float*)d_in[3];
    const float* W2  = (const float*)d_in[4];
    const float* S0  = (const float*)d_in[5];
    const float* S1  = (const float*)d_in[6];
    const float* S2  = (const float*)d_in[7];
    float* out = (float*)d_out;

    char* w = (char*)d_ws;
    size_t off = 0;
    auto alloc = [&](size_t b) { size_t r = off; off = (off + b + 255) & ~(size_t)255; return r; };
    unsigned* hists = (unsigned*)(w + alloc(4 * 256 * 4));   // hists[pass][256]
    float* colsum   = (float*)(w + alloc(HH * 4));
    float* stats    = (float*)(w + alloc(256));
    size_t zero_end = off;
    int* nnz   = (int*)(w + alloc(NN * 4));
    int* colsI = (int*)(w + alloc((size_t)NN * MAXNBR * 4));
    float* dis = (float*)(w + alloc(NN * 4));
    unsigned short* xh  = (unsigned short*)(w + alloc((size_t)NN * FF * 2));
    unsigned short* xl  = (unsigned short*)(w + alloc((size_t)NN * FF * 2));
    unsigned short* W0h = (unsigned short*)(w + alloc((size_t)HH * FF * 2));
    unsigned short* W0l = (unsigned short*)(w + alloc((size_t)HH * FF * 2));
    unsigned short* W1h = (unsigned short*)(w + alloc((size_t)HH * HH * 2));
    unsigned short* W1l = (unsigned short*)(w + alloc((size_t)HH * HH * 2));
    unsigned short* W2h = (unsigned short*)(w + alloc((size_t)CC * HH * 2));
    unsigned short* W2l = (unsigned short*)(w + alloc((size_t)CC * HH * 2));
    unsigned short* hAh = (unsigned short*)(w + alloc((size_t)NN * HH * 2));
    unsigned short* hAl = (unsigned short*)(w + alloc((size_t)NN * HH * 2));
    float* hB   = (float*)(w + alloc((size_t)NN * HH * 4));
    float* hAgg = (float*)(w + alloc((size_t)NN * HH * 4));
    unsigned short* hBh = (unsigned short*)(w + alloc((size_t)NN * HH * 2));
    unsigned short* hBl = (unsigned short*)(w + alloc((size_t)NN * HH * 2));
    float* h3   = (float*)(w + alloc((size_t)NN * CC * 4));
    (void)ws_size; (void)in_sizes; (void)n_in; (void)out_size;

    hipMemsetAsync(d_ws, 0, zero_end, stream);

    // threshold: exact radix select, 4 x 8-bit histogram passes (selects re-derived in-block)
    for (int p = 0; p < 4; ++p)
        hist8_kernel<<<256, 256, 0, stream>>>(S0, S1, S2, hists, p);

    // fused: masked weights -> hi/lo bf16  AND  x -> hi/lo bf16
    mask_split_fused<<<MASKB + NN * FF / 4 / 256, 256, 0, stream>>>(
        W0, W1, W2, S0, S1, S2, hists, W0h, W0l, W1h, W1l, W2h, W2l, x, xh, xl);

    // gemm1 (x @ Wm0^T -> split) + first half of deg; gemm2 (+ second half of deg)
    const int g12 = (NN / 64) * (HH / 128);   // 512 gemm blocks
    gemm_hl<64, 128, 1><<<g12 + NN / 2, 256, 0, stream>>>(
        xh, xl, W0h, W0l, nullptr, hAh, hAl, HH, HH / 128, g12,
        adj, nnz, colsI, dis, 0);
    gemm_hl<64, 128, 0><<<g12 + NN / 2, 256, 0, stream>>>(
        hAh, hAl, W1h, W1l, hB, nullptr, nullptr, HH, HH / 128, g12,
        adj, nnz, colsI, dis, NN / 2);

    // aggregation
    spmm512<<<NN, 128, 0, stream>>>(nnz, colsI, dis, hB, hAgg);

    // pairnorm stats (single fused pass) + apply+relu -> hi/lo bf16
    colstats_kernel<<<256, 256, 0, stream>>>(hAgg, colsum, stats);
    pn_apply_split<<<(NN * HH / 4) / 256, 256, 0, stream>>>(hAgg, colsum, stats, hBh, hBl);

    // h3 = hB @ Wm2^T ; out = adj_n @ h3
    const int g3 = (NN / 32) * (CC / 64);     // 256 blocks
    gemm_hl<32, 64, 0><<<g3, 256, 0, stream>>>(
        hBh, hBl, W2h, W2l, h3, nullptr, nullptr, CC, CC / 64, g3,
        nullptr, nullptr, nullptr, nullptr, 0);
    spmm64<<<NN, 64, 0, stream>>>(nnz, colsI, dis, h3, out);
}